// Round 3
// baseline (255.574 us; speedup 1.0000x reference)
//
#include <hip/hip_runtime.h>

// ---------- types ----------
typedef __attribute__((ext_vector_type(8))) short short8;
typedef __attribute__((ext_vector_type(8), may_alias)) short short8a;
typedef __attribute__((ext_vector_type(4))) short short4a_ __attribute__((may_alias));
typedef __attribute__((ext_vector_type(2), may_alias)) short short2a;
typedef __attribute__((ext_vector_type(4))) float float4_;
typedef __attribute__((ext_vector_type(4), may_alias)) float float4a;
typedef __attribute__((ext_vector_type(2), may_alias)) float float2a;

__device__ __forceinline__ float b2f(short h) {
  unsigned int u = ((unsigned int)(unsigned short)h) << 16;
  return __builtin_bit_cast(float, u);
}
__device__ __forceinline__ short f2b(float f) {
  unsigned int u = __builtin_bit_cast(unsigned int, f);
  u += 0x7fffu + ((u >> 16) & 1u);   // RNE
  return (short)(unsigned short)(u >> 16);
}

#define GLOBAL_AS __attribute__((address_space(1)))
#define LDS_AS    __attribute__((address_space(3)))
__device__ __forceinline__ void async_copy16(void* lds, const void* g) {
  __builtin_amdgcn_global_load_lds((GLOBAL_AS const void*)g, (LDS_AS void*)lds, 16, 0, 0);
}

// ---------- 1. fused prep: x->bf16, Wq|Wk|Wv transpose (q-scale folded), Wo transpose, rope table ----------
__global__ __launch_bounds__(256) void prep(const float* __restrict__ x,
                                            const float* __restrict__ Wq,
                                            const float* __restrict__ Wk,
                                            const float* __restrict__ Wv,
                                            const float* __restrict__ Wo,
                                            short* __restrict__ xb,
                                            short* __restrict__ wqkvt,
                                            short* __restrict__ wot,
                                            float* __restrict__ rtab) {
  __shared__ float tile[64][65];
  int bid = blockIdx.x;
  if (bid < 1536) {                     // Wq|Wk|Wv -> [3072][2048] bf16 (B^T)
    int k0 = (bid & 31) * 64, n0 = (bid >> 5) * 64;
    for (int idx = threadIdx.x; idx < 4096; idx += 256) {
      int r = idx >> 6, cc = idx & 63;
      int n = n0 + cc;
      float v;
      if (n < 2048)      v = Wq[(size_t)(k0 + r) * 2048 + n] * 0.08838834764831845f; // fold 1/sqrt(128)
      else if (n < 2560) v = Wk[(size_t)(k0 + r) * 512 + (n - 2048)];
      else               v = Wv[(size_t)(k0 + r) * 512 + (n - 2560)];
      tile[r][cc] = v;
    }
    __syncthreads();
    for (int idx = threadIdx.x; idx < 4096; idx += 256) {
      int r = idx >> 6, cc = idx & 63;
      wqkvt[(size_t)(n0 + r) * 2048 + k0 + cc] = f2b(tile[cc][r]);
    }
  } else if (bid < 2560) {              // Wo -> [2048][2048] bf16 (B^T)
    int t = bid - 1536;
    int k0 = (t & 31) * 64, n0 = (t >> 5) * 64;
    for (int idx = threadIdx.x; idx < 4096; idx += 256) {
      int r = idx >> 6, cc = idx & 63;
      tile[r][cc] = Wo[(size_t)(k0 + r) * 2048 + n0 + cc];
    }
    __syncthreads();
    for (int idx = threadIdx.x; idx < 4096; idx += 256) {
      int r = idx >> 6, cc = idx & 63;
      wot[(size_t)(n0 + r) * 2048 + k0 + cc] = f2b(tile[cc][r]);
    }
  } else if (bid < 10752) {             // x fp32 -> bf16
    int i = (bid - 2560) * 256 + threadIdx.x;
    float4a v = ((const float4a*)x)[i];
    short4a_ o;
    o.x = f2b(v.x); o.y = f2b(v.y); o.z = f2b(v.z); o.w = f2b(v.w);
    ((short4a_*)xb)[i] = o;
  } else {                              // rope table: rtab[(pos*64+i)*2] = {cos, sin}
    int idx = (bid - 10752) * 256 + threadIdx.x;   // 0..65535
    int pos = idx >> 6, i = idx & 63;
    float inv = exp2f((float)i * -0.20762050593478f);  // 10000^(-2i/128)
    float s, c;
    sincosf((float)pos * inv, &s, &c);
    float2a cs; cs.x = c; cs.y = s;
    ((float2a*)rtab)[idx] = cs;
  }
}

// ---------- 2. GEMM  C[M][N] = A[M][K] * B^T[N][K] ----------
// BM=128 x BN(384|256), BK=64, 8 waves (2M x 4N; per-wave 64 x BN/4), 100% grid fill.
// DENSE phase = one consumption group g=(tile,kh): 4xNF MFMA (24|16) per phase,
// 2 phases per K-tile, 2 barriers per phase (4/K-tile). Stage group g+3 during
// phase g (LPG loads); at phase end wait vmcnt(2*LPG) -> retires g+1 (issued ~2.5
// phases earlier, ~2500cy >= HBM latency); 2 groups always in flight. Never
// vmcnt(0) mid-loop. (Round-2 lesson: 12-MFMA half-phases with 8 barriers/K-tile
// left MfmaUtil at 34% -- per-phase fixed cost must amortize over >=16 MFMA.)
// LDS per buffer: [A kh0 4K][A kh1 4K][B kh0 BBUF][B kh1 BBUF] shorts; chunk
// swizzle chunk^((row>>1)&3) via pre-swizzled global source (linear LDS dest),
// read applies same XOR (2-way = free).
// MODE 0: fp32 direct store. MODE 1: per-head epilogue (head<20 rope -> qkv, else V^T -> vt).
#define FENCE() __builtin_amdgcn_sched_barrier(0)

template <int N_>
__device__ __forceinline__ void waitv() {
  if constexpr (N_ == 8)      asm volatile("s_waitcnt vmcnt(8)" ::: "memory");
  else if constexpr (N_ == 6) asm volatile("s_waitcnt vmcnt(6)" ::: "memory");
  else if constexpr (N_ == 4) asm volatile("s_waitcnt vmcnt(4)" ::: "memory");
  else if constexpr (N_ == 3) asm volatile("s_waitcnt vmcnt(3)" ::: "memory");
  else                        asm volatile("s_waitcnt vmcnt(0)" ::: "memory");
}

// stage group (T_,KH_) into parity P_; part 0 = A + B.slab0 (2 loads), part 1 = B.slab1(+slab2)
#define STG(P_, KH_, T_, PART_)                                                    \
  do { if ((T_) < nK) {                                                            \
    const size_t co_ = (size_t)(T_) * 64 + (KH_) * 32;                             \
    if ((PART_) == 0) {                                                            \
      async_copy16(&lsm[(P_) * BUFSZ + (KH_) * 4096 + wave * 512], Asrc + co_);    \
      async_copy16(&lsm[(P_) * BUFSZ + 8192 + (KH_) * BBUF + wave * 512],          \
                   Bsrc + co_);                                                    \
    } else {                                                                       \
      async_copy16(&lsm[(P_) * BUFSZ + 8192 + (KH_) * BBUF + 4096 + wave * 512],   \
                   Bsrc + 128 * (size_t)K + co_);                                  \
      if (BSLAB == 3)                                                              \
        async_copy16(&lsm[(P_) * BUFSZ + 8192 + (KH_) * BBUF + 8192 + wave * 512], \
                     Bsrc + 256 * (size_t)K + co_);                                \
    }                                                                              \
  } } while (0)

#define WAITG(G_)                                                                  \
  do { int rem_ = 2 * nK - 2 - (G_);                                               \
    if (rem_ >= 2) waitv<2 * LPG>();                                               \
    else if (rem_ == 1) waitv<LPG>();                                              \
    else waitv<0>(); } while (0)

// dense phase: consume group (P_,KK_) fully -- 4xNF MFMA, stage one group, 2 barriers
#define PHASED(P_, KK_, STAGE0, STAGE1, ENDW)                                      \
  {                                                                                \
    short8 af[4];                                                                  \
    _Pragma("unroll") for (int mi = 0; mi < 4; ++mi)                               \
      af[mi] = *(const short8a*)&lsm[(P_) * BUFSZ + (KK_) * 4096 + aoff[mi]];      \
    short8 bf[NF];                                                                 \
    _Pragma("unroll") for (int ni = 0; ni < NF; ++ni)                              \
      bf[ni] = *(const short8a*)&lsm[(P_) * BUFSZ + 8192 + (KK_) * BBUF +          \
                                     boff[ni]];                                    \
    STAGE0; STAGE1;                                                                \
    FENCE();                                                                       \
    __builtin_amdgcn_s_barrier();                                                  \
    FENCE();                                                                       \
    __builtin_amdgcn_s_setprio(1);                                                 \
    _Pragma("unroll") for (int mi = 0; mi < 4; ++mi)                               \
      _Pragma("unroll") for (int ni = 0; ni < NF; ++ni)                            \
        acc[mi][ni] = __builtin_amdgcn_mfma_f32_16x16x32_bf16(                     \
            af[mi], bf[ni], acc[mi][ni], 0, 0, 0);                                 \
    __builtin_amdgcn_s_setprio(0);                                                 \
    FENCE();                                                                       \
    ENDW;                                                                          \
    __builtin_amdgcn_s_barrier();                                                  \
    FENCE();                                                                       \
  }

template <int MODE, int BN>
__global__ __launch_bounds__(512, 2)
void gemm_bt(const short* __restrict__ A, const short* __restrict__ B,
             void* __restrict__ Cv, const float* __restrict__ rtab,
             short* __restrict__ vt, int M, int N, int K) {
  constexpr int NF = BN / 64;          // n-frags per wave (6 | 4)
  constexpr int BSLAB = BN / 128;      // B 128-row slabs (3 | 2)
  constexpr int LPG = 1 + BSLAB;       // staging loads per group per thread (4 | 3)
  constexpr int BBUF = BSLAB * 4096;   // shorts per B kh-slab
  constexpr int BUFSZ = 8192 + 2 * BBUF;
  __shared__ alignas(16) short lsm[2 * BUFSZ];   // 128 KiB | 96 KiB
  const int tid = threadIdx.x;
  const int wave = tid >> 6, lane = tid & 63;
  const int quad = lane >> 4, l16 = lane & 15;
  const int m0 = blockIdx.x * 128, n0 = blockIdx.y * BN;
  const int wm = (wave >> 2) * 64, wn = (wave & 3) * (BN / 4);
  const int nK = K >> 6;               // even, >= 2

  // thread-constant LDS fragment offsets (shorts), swizzle folded in
  int aoff[4], boff[NF];
#pragma unroll
  for (int j = 0; j < 4; ++j) {
    int r = wm + j * 16 + l16;
    aoff[j] = r * 32 + (quad ^ ((r >> 1) & 3)) * 8;
  }
#pragma unroll
  for (int ni = 0; ni < NF; ++ni) {
    int r = wn + ni * 16 + l16;
    boff[ni] = r * 32 + (quad ^ ((r >> 1) & 3)) * 8;
  }
  // staging: thread ti -> LDS (row ti>>2, chunk ti&3); holds global chunk (ti&3)^((row>>1)&3)
  const int r0 = tid >> 2;
  const int qq = (tid & 3) ^ ((r0 >> 1) & 3);   // invariant under row+128/+256
  const short* Asrc = A + (size_t)(m0 + r0) * K + qq * 8;
  const short* Bsrc = B + (size_t)(n0 + r0) * K + qq * 8;

  float4_ acc[4][NF];
#pragma unroll
  for (int i = 0; i < 4; i++)
#pragma unroll
    for (int j = 0; j < NF; j++) acc[i][j] = (float4_){0.f, 0.f, 0.f, 0.f};

  // prologue: stage groups 0,1,2; retire group 0 (keep 1,2 in flight)
  STG(0, 0, 0, 0); STG(0, 0, 0, 1);
  STG(0, 1, 0, 0); STG(0, 1, 0, 1);
  STG(1, 0, 1, 0); STG(1, 0, 1, 1);
  FENCE();
  waitv<2 * LPG>();
  __builtin_amdgcn_s_barrier();
  FENCE();

  for (int t = 0; t < nK; t += 2) {
    PHASED(0, 0, STG(1, 1, t + 1, 0), STG(1, 1, t + 1, 1), WAITG(2 * t));
    PHASED(0, 1, STG(0, 0, t + 2, 0), STG(0, 0, t + 2, 1), WAITG(2 * t + 1));
    PHASED(1, 0, STG(0, 1, t + 2, 0), STG(0, 1, t + 2, 1), WAITG(2 * t + 2));
    PHASED(1, 1, STG(1, 0, t + 3, 0), STG(1, 0, t + 3, 1), WAITG(2 * t + 3));
  }

  if (MODE == 1) {
    constexpr int LCS = BN + 4;               // 388: 8-row stride -> bank+16 (2-way free)
    short* lC = lsm;                          // [128][LCS] bf16, single pass
    const int posBase = m0 & 1023;
    short* Cb = (short*)Cv;
    __syncthreads();
#pragma unroll
    for (int mt = 0; mt < 4; ++mt)
#pragma unroll
      for (int ni = 0; ni < NF; ++ni)
#pragma unroll
        for (int r = 0; r < 4; r++)
          lC[(wm + mt * 16 + quad * 4 + r) * LCS + wn + ni * 16 + l16] = f2b(acc[mt][ni][r]);
    __syncthreads();
    const int hb = n0 >> 7;                   // 3 heads per tile; head<20 rope, else V
#pragma unroll
    for (int hh = 0; hh < 3; ++hh) {
      const int H = hb + hh;
      if (H < 20) {                           // rope: 128 rows x 32 col-pair groups
        for (int it = 0; it < 8; ++it) {
          int idx = it * 512 + tid;
          int row = idx >> 5;
          int c2 = (idx & 31) * 2;            // pair (c2, c2+64)
          float4a tt = *(const float4a*)&rtab[((size_t)(posBase + row) * 64 + c2) * 2];
          short2a t1 = *(const short2a*)&lC[row * LCS + hh * 128 + c2];
          short2a t2 = *(const short2a*)&lC[row * LCS + hh * 128 + c2 + 64];
          float t1a = b2f(t1.x), t1b = b2f(t1.y);
          float t2a = b2f(t2.x), t2b = b2f(t2.y);
          short2a o1, o2;
          o1.x = f2b(t1a * tt.x - t2a * tt.y); o1.y = f2b(t1b * tt.z - t2b * tt.w);
          o2.x = f2b(t2a * tt.x + t1a * tt.y); o2.y = f2b(t2b * tt.z + t1b * tt.w);
          size_t base = (size_t)(m0 + row) * N + n0 + hh * 128;
          *(short2a*)&Cb[base + c2] = o1;
          *(short2a*)&Cb[base + c2 + 64] = o2;
        }
      } else {                                // V head: transpose into vt[(b*4+hv)*128+d][seq]
        const int hv = H - 20;
        const int bb = m0 >> 10;
        for (int it = 0; it < 4; ++it) {
          int idx = it * 512 + tid;           // 128 d x 16 jc
          int d = idx >> 4, jc = idx & 15;
          short8 v;
#pragma unroll
          for (int k = 0; k < 8; ++k) v[k] = lC[(jc * 8 + k) * LCS + hh * 128 + d];
          *(short8a*)&vt[(size_t)((bb * 4 + hv) * 128 + d) * 1024 + posBase + jc * 8] = v;
        }
      }
    }
  } else {
    float* Cf = (float*)Cv;
#pragma unroll
    for (int mt = 0; mt < 4; ++mt)
#pragma unroll
      for (int ni = 0; ni < NF; ++ni) {
        int row = m0 + wm + mt * 16 + quad * 4;
        int col = n0 + wn + ni * 16 + l16;
        float4_ v = acc[mt][ni];
#pragma unroll
        for (int r = 0; r < 4; r++) Cf[(size_t)(row + r) * N + col] = v[r];
      }
  }
}

// ---------- 3. GQA causal flash attention (no-max softmax; 128-row Q tiles) ----------
// grid (64 = b*16+h, 8 qtiles reversed), 256 threads = 4 waves x (2 groups x 16 q-rows)
__global__ __launch_bounds__(256, 2)
void flash(const short* __restrict__ qkv, const short* __restrict__ vt,
           const float* __restrict__ head_scale, short* __restrict__ attn) {
  __shared__ alignas(16) short lK[64 * 128];   // [krow][d-chunk swizzled]
  __shared__ alignas(16) short lV[128 * 64];   // [d][krow-chunk swizzled]
  __shared__ alignas(16) short lP[4][32 * 72]; // per-wave P (32 rows), padded stride 72
  const int tid = threadIdx.x, wave = tid >> 6, lane = tid & 63;
  const int quad = lane >> 4, l16 = lane & 15;
  const int bh = blockIdx.x, b = bh >> 4, h = bh & 15, kv = h >> 2;
  const int qt = 7 - blockIdx.y;               // heavy blocks first
  const int base_w = qt * 128 + wave * 32;     // wave's first q-row
  short8 qf[2][4];
#pragma unroll
  for (int g = 0; g < 2; g++) {
    int qrow = base_w + g * 16 + l16;
    const short* qp = qkv + (size_t)(b * 1024 + qrow) * 3072 + h * 128;
#pragma unroll
    for (int kc = 0; kc < 4; kc++) qf[g][kc] = *(const short8a*)(qp + kc * 32 + quad * 8);
  }
  float4_ O[2][8];
#pragma unroll
  for (int g = 0; g < 2; g++)
#pragma unroll
    for (int i = 0; i < 8; i++) O[g][i] = (float4_){0.f, 0.f, 0.f, 0.f};
  float rsacc[2][4] = {{0.f, 0.f, 0.f, 0.f}, {0.f, 0.f, 0.f, 0.f}};
  const size_t kbase = (size_t)(b * 1024) * 3072 + 2048 + kv * 128;
  const size_t vbase = (size_t)((b * 4 + kv) * 128) * 1024;
  const int slot16 = lane & 15, rr4 = lane >> 4;
  const int slot8 = lane & 7, dr8 = lane >> 3;
  const int nkt = 2 * qt + 2;
  for (int kt = 0; kt < nkt; ++kt) {
    __syncthreads();
#pragma unroll
    for (int cc = 0; cc < 4; ++cc) {           // K tile: 64 rows x 128 d
      int rb = wave * 16 + cc * 4;
      int r = rb + rr4;
      int c = slot16 ^ (r & 15);
      async_copy16(&lK[rb * 128], qkv + kbase + (size_t)(kt * 64 + r) * 3072 + c * 8);
    }
#pragma unroll
    for (int cc = 0; cc < 4; ++cc) {           // V tile: 128 d x 64 rows
      int db = wave * 32 + cc * 8;
      int d = db + dr8;
      int c = slot8 ^ (d & 7);
      async_copy16(&lV[db * 64], vt + vbase + (size_t)d * 1024 + kt * 64 + c * 8);
    }
    __syncthreads();
    if (kt * 64 > base_w + 31) continue;       // wave fully below diagonal (uniform)
    // S = Q K^T, both groups share kf
    float4_ S[2][4];
#pragma unroll
    for (int st = 0; st < 4; ++st) {
      float4_ s0 = (float4_){0.f, 0.f, 0.f, 0.f}, s1 = s0;
      int kr = st * 16 + l16;
#pragma unroll
      for (int kc = 0; kc < 4; ++kc) {
        int c = kc * 4 + quad;
        short8 kf = *(const short8a*)&lK[kr * 128 + (c ^ (kr & 15)) * 8];
        s0 = __builtin_amdgcn_mfma_f32_16x16x32_bf16(qf[0][kc], kf, s0, 0, 0, 0);
        s1 = __builtin_amdgcn_mfma_f32_16x16x32_bf16(qf[1][kc], kf, s1, 0, 0, 0);
      }
      S[0][st] = s0; S[1][st] = s1;
    }
    // causal mask + exp + P store
#pragma unroll
    for (int g = 0; g < 2; g++) {
      int gbase = base_w + g * 16;
      if (kt * 64 + 63 > gbase) {
#pragma unroll
        for (int st = 0; st < 4; ++st)
#pragma unroll
          for (int r = 0; r < 4; r++)
            if (kt * 64 + st * 16 + l16 > gbase + quad * 4 + r) S[g][st][r] = -1e30f;
      }
#pragma unroll
      for (int st = 0; st < 4; ++st)
#pragma unroll
        for (int r = 0; r < 4; r++) {
          float pv = __expf(S[g][st][r]);
          rsacc[g][r] += pv;
          lP[wave][(g * 16 + quad * 4 + r) * 72 + st * 16 + l16] = f2b(pv);
        }
    }
    short8 pf[2][2];
#pragma unroll
    for (int g = 0; g < 2; g++)
#pragma unroll
      for (int kc2 = 0; kc2 < 2; kc2++)
        pf[g][kc2] = *(const short8a*)&lP[wave][(g * 16 + l16) * 72 + kc2 * 32 + quad * 8];
#pragma unroll
    for (int dt = 0; dt < 8; ++dt) {
      int d = dt * 16 + l16;
#pragma unroll
      for (int kc2 = 0; kc2 < 2; kc2++) {
        int c = kc2 * 4 + quad;
        short8 vf = *(const short8a*)&lV[d * 64 + (c ^ (d & 7)) * 8];
        O[0][dt] = __builtin_amdgcn_mfma_f32_16x16x32_bf16(pf[0][kc2], vf, O[0][dt], 0, 0, 0);
        O[1][dt] = __builtin_amdgcn_mfma_f32_16x16x32_bf16(pf[1][kc2], vf, O[1][dt], 0, 0, 0);
      }
    }
  }
  float hs = head_scale[h];
#pragma unroll
  for (int g = 0; g < 2; g++) {
    float l_i[4];
#pragma unroll
    for (int r = 0; r < 4; r++) {
      float rs = rsacc[g][r];
#pragma unroll
      for (int off = 8; off; off >>= 1) rs += __shfl_xor(rs, off, 64);
      l_i[r] = rs;
    }
    int qrow = base_w + g * 16 + quad * 4;
#pragma unroll
    for (int dt = 0; dt < 8; ++dt) {
      int col = h * 128 + dt * 16 + l16;
#pragma unroll
      for (int r = 0; r < 4; r++) {
        float o = O[g][dt][r] * (hs / l_i[r]);
        attn[(size_t)(b * 1024 + qrow + r) * 2048 + col] = f2b(o);
      }
    }
  }
}

// ---------- launch ----------
extern "C" void kernel_launch(void* const* d_in, const int* in_sizes, int n_in,
                              void* d_out, int out_size, void* d_ws, size_t ws_size,
                              hipStream_t stream) {
  const float* x  = (const float*)d_in[0];
  const float* Wq = (const float*)d_in[1];
  const float* Wk = (const float*)d_in[2];
  const float* Wv = (const float*)d_in[3];
  const float* Wo = (const float*)d_in[4];
  const float* hs = (const float*)d_in[5];
  float* out = (float*)d_out;
  char* ws = (char*)d_ws;
  // ws layout (64 MB total)
  short* xb    = (short*)(ws);                  // 16 MB  [4096][2048]   (reused as attn)
  short* wqkvt = (short*)(ws + 16777216);       // 12 MB  [3072][2048]
  short* wot   = (short*)(ws + 29360128);       //  8 MB  [2048][2048]
  short* qkv   = (short*)(ws + 37748736);       // 24 MB  [4096][3072] (V cols unused)
  short* vt    = (short*)(ws + 62914560);       //  4 MB  [2048][1024]
  short* attn  = xb;                            // alias: xb dead after GEMM1
  // rope table lives in d_out's tail: d_out (32 MB fp32) is dead until GEMM2 fully overwrites it
  float* rtab  = out + 8257536;                 // 512 KB = 131072 floats

  prep<<<11008, 256, 0, stream>>>(x, Wq, Wk, Wv, Wo, xb, wqkvt, wot, rtab);
  gemm_bt<1, 384><<<dim3(32, 8), 512, 0, stream>>>(xb, wqkvt, (void*)qkv, rtab, vt, 4096, 3072, 2048);
  flash<<<dim3(64, 8), 256, 0, stream>>>(qkv, vt, hs, attn);
  gemm_bt<0, 256><<<dim3(32, 8), 512, 0, stream>>>(attn, wot, (void*)out, nullptr, nullptr, 4096, 2048, 2048);
}

// Round 4
// 255.425 us; speedup vs baseline: 1.0006x; 1.0006x over previous
//
#include <hip/hip_runtime.h>

// ---------- types ----------
typedef __attribute__((ext_vector_type(8))) short short8;
typedef __attribute__((ext_vector_type(8), may_alias)) short short8a;
typedef __attribute__((ext_vector_type(4))) short short4a_ __attribute__((may_alias));
typedef __attribute__((ext_vector_type(2), may_alias)) short short2a;
typedef __attribute__((ext_vector_type(4))) float float4_;
typedef __attribute__((ext_vector_type(4), may_alias)) float float4a;
typedef __attribute__((ext_vector_type(2), may_alias)) float float2a;

__device__ __forceinline__ float b2f(short h) {
  unsigned int u = ((unsigned int)(unsigned short)h) << 16;
  return __builtin_bit_cast(float, u);
}
__device__ __forceinline__ short f2b(float f) {
  unsigned int u = __builtin_bit_cast(unsigned int, f);
  u += 0x7fffu + ((u >> 16) & 1u);   // RNE
  return (short)(unsigned short)(u >> 16);
}

#define GLOBAL_AS __attribute__((address_space(1)))
#define LDS_AS    __attribute__((address_space(3)))
__device__ __forceinline__ void async_copy16(void* lds, const void* g) {
  __builtin_amdgcn_global_load_lds((GLOBAL_AS const void*)g, (LDS_AS void*)lds, 16, 0, 0);
}

// ---------- 1. fused prep: x->bf16, Wq|Wk|Wv transpose (q-scale folded), Wo transpose, rope table ----------
// grid: [0,1536) wqkv tiles, [1536,2560) wo tiles, [2560,10752) cvt blocks, [10752,11008) rope table
__global__ __launch_bounds__(256) void prep(const float* __restrict__ x,
                                            const float* __restrict__ Wq,
                                            const float* __restrict__ Wk,
                                            const float* __restrict__ Wv,
                                            const float* __restrict__ Wo,
                                            short* __restrict__ xb,
                                            short* __restrict__ wqkvt,
                                            short* __restrict__ wot,
                                            float* __restrict__ rtab) {
  __shared__ float tile[64][65];
  int bid = blockIdx.x;
  if (bid < 1536) {                     // Wq|Wk|Wv -> [3072][2048] bf16 (B^T)
    int k0 = (bid & 31) * 64, n0 = (bid >> 5) * 64;
    for (int idx = threadIdx.x; idx < 4096; idx += 256) {
      int r = idx >> 6, cc = idx & 63;
      int n = n0 + cc;
      float v;
      if (n < 2048)      v = Wq[(size_t)(k0 + r) * 2048 + n] * 0.08838834764831845f; // fold 1/sqrt(128)
      else if (n < 2560) v = Wk[(size_t)(k0 + r) * 512 + (n - 2048)];
      else               v = Wv[(size_t)(k0 + r) * 512 + (n - 2560)];
      tile[r][cc] = v;
    }
    __syncthreads();
    for (int idx = threadIdx.x; idx < 4096; idx += 256) {
      int r = idx >> 6, cc = idx & 63;
      wqkvt[(size_t)(n0 + r) * 2048 + k0 + cc] = f2b(tile[cc][r]);
    }
  } else if (bid < 2560) {              // Wo -> [2048][2048] bf16 (B^T)
    int t = bid - 1536;
    int k0 = (t & 31) * 64, n0 = (t >> 5) * 64;
    for (int idx = threadIdx.x; idx < 4096; idx += 256) {
      int r = idx >> 6, cc = idx & 63;
      tile[r][cc] = Wo[(size_t)(k0 + r) * 2048 + n0 + cc];
    }
    __syncthreads();
    for (int idx = threadIdx.x; idx < 4096; idx += 256) {
      int r = idx >> 6, cc = idx & 63;
      wot[(size_t)(n0 + r) * 2048 + k0 + cc] = f2b(tile[cc][r]);
    }
  } else if (bid < 10752) {             // x fp32 -> bf16
    int i = (bid - 2560) * 256 + threadIdx.x;
    float4a v = ((const float4a*)x)[i];
    short4a_ o;
    o.x = f2b(v.x); o.y = f2b(v.y); o.z = f2b(v.z); o.w = f2b(v.w);
    ((short4a_*)xb)[i] = o;
  } else {                              // rope table: rtab[(pos*64+i)*2] = {cos, sin}
    int idx = (bid - 10752) * 256 + threadIdx.x;   // 0..65535
    int pos = idx >> 6, i = idx & 63;
    float inv = exp2f((float)i * -0.20762050593478f);  // 10000^(-2i/128)
    float s, c;
    sincosf((float)pos * inv, &s, &c);
    float2a cs; cs.x = c; cs.y = s;
    ((float2a*)rtab)[idx] = cs;
  }
}

// ---------- 2. GEMM  C[M][N] = A[M][K] * B^T[N][K] ----------
// Round-0 proven structure (891 TF): 128x128 tile, BK=64, 4 waves, 2-phase K-loop,
// global_load_lds(16B), XOR chunk swizzle (chunk' = chunk ^ (row&7)).
// ROUND-4 CHANGE: __launch_bounds__(256,4) -> request 4 blocks/CU (was 2).
// LDS 33.8KB x 4 = 135KB <= 160KB; VGPR cap 128 >= 68 used. Theory: 4 independent
// barrier groups per CU let one block's MFMA cover another's vmcnt(0)+barrier
// drain (the documented ~20% m97-structure stall). 8-phase ports (rounds 1-3,
// 1 block/CU) all regressed to 798-852 TF -- intra-block overlap didn't
// reproduce; cross-block overlap is the remaining proven lever (m114).
// MODE 0: fp32 direct store.
// MODE 1: bf16; n0<2560 -> fused RoPE (table, loads hoisted) -> qkv; n0>=2560 -> transposed V -> vt.
template <int MODE>
__global__ __launch_bounds__(256, 4)
void gemm_bt(const short* __restrict__ A, const short* __restrict__ B,
             void* __restrict__ Cv, const float* __restrict__ rtab,
             short* __restrict__ vt, int M, int N, int K) {
  __shared__ alignas(16) short lsm[MODE == 1 ? 16896 : 16384];
  short* lA = lsm;
  short* lB = lsm + 8192;
  const int tid = threadIdx.x;
  const int wave = tid >> 6, lane = tid & 63;
  const int quad = lane >> 4, l16 = lane & 15;
  const int m0 = blockIdx.x * 128, n0 = blockIdx.y * 128;
  const int wm = (wave >> 1) * 64, wn = (wave & 1) * 64;
  float4_ acc[4][4];
#pragma unroll
  for (int i = 0; i < 4; i++)
#pragma unroll
    for (int j = 0; j < 4; j++) acc[i][j] = (float4_){0.f, 0.f, 0.f, 0.f};
  const int nK = K >> 6;
  const int srow = lane >> 3, slot = lane & 7;
  for (int kt = 0; kt < nK; ++kt) {
    __syncthreads();
#pragma unroll
    for (int cth = 0; cth < 4; ++cth) {
      int rb = wave * 32 + cth * 8;
      int r = rb + srow;
      int c = slot ^ (r & 7);
      async_copy16(&lA[rb * 64], A + (size_t)(m0 + r) * K + kt * 64 + c * 8);
      async_copy16(&lB[rb * 64], B + (size_t)(n0 + r) * K + kt * 64 + c * 8);
    }
    __syncthreads();
#pragma unroll
    for (int kc = 0; kc < 2; ++kc) {
      short8 af[4], bf[4];
      int cch = kc * 4 + quad;
#pragma unroll
      for (int mt = 0; mt < 4; ++mt) {
        int ar = wm + mt * 16 + l16;
        af[mt] = *(const short8a*)&lA[ar * 64 + (cch ^ (ar & 7)) * 8];
      }
#pragma unroll
      for (int nt = 0; nt < 4; ++nt) {
        int br = wn + nt * 16 + l16;
        bf[nt] = *(const short8a*)&lB[br * 64 + (cch ^ (br & 7)) * 8];
      }
#pragma unroll
      for (int mt = 0; mt < 4; ++mt)
#pragma unroll
        for (int nt = 0; nt < 4; ++nt)
          acc[mt][nt] = __builtin_amdgcn_mfma_f32_16x16x32_bf16(af[mt], bf[nt], acc[mt][nt], 0, 0, 0);
    }
  }
  if (MODE == 1) {
    const bool isRope = (n0 < 2560);    // block-uniform
    __syncthreads();                    // staging LDS now dead
    short* lC = lsm;                    // [128][132] bf16
    const int posBase = m0 & 1023;
    float4a tv[16];
    if (isRope) {                       // hoist table loads: latency hidden behind lC writes + barrier
#pragma unroll
      for (int it = 0; it < 16; ++it) {
        int idx = it * 256 + tid;
        int row = idx >> 5, c2 = (idx & 31) * 2;
        tv[it] = *(const float4a*)&rtab[((size_t)(posBase + row) * 64 + c2) * 2];
      }
    }
#pragma unroll
    for (int mt = 0; mt < 4; ++mt)
#pragma unroll
      for (int nt = 0; nt < 4; ++nt)
#pragma unroll
        for (int r = 0; r < 4; r++)
          lC[(wm + mt * 16 + quad * 4 + r) * 132 + wn + nt * 16 + l16] = f2b(acc[mt][nt][r]);
    __syncthreads();
    if (isRope) {
      short* Cb = (short*)Cv;
#pragma unroll
      for (int it = 0; it < 16; ++it) {
        int idx = it * 256 + tid;       // 0..4095
        int row = idx >> 5;             // 0..127
        int c2 = (idx & 31) * 2;        // pair indices c2, c2+1 (in [0,64))
        short2a t1 = *(const short2a*)&lC[row * 132 + c2];
        short2a t2 = *(const short2a*)&lC[row * 132 + c2 + 64];
        float t1a = b2f(t1.x), t1b = b2f(t1.y);
        float t2a = b2f(t2.x), t2b = b2f(t2.y);
        float4a t = tv[it];             // ca,sa,cb,sb
        short2a o1, o2;
        o1.x = f2b(t1a * t.x - t2a * t.y); o1.y = f2b(t1b * t.z - t2b * t.w);
        o2.x = f2b(t2a * t.x + t1a * t.y); o2.y = f2b(t2b * t.z + t1b * t.w);
        size_t base = (size_t)(m0 + row) * N + n0;
        *(short2a*)&Cb[base + c2] = o1;
        *(short2a*)&Cb[base + c2 + 64] = o2;
      }
    } else {
      // V block: transposed store into vt[(b*4+kv)*128+d][seq]
      const int bkv = (m0 >> 10) * 4 + ((n0 - 2560) >> 7);
#pragma unroll
      for (int it = 0; it < 8; ++it) {
        int idx = it * 256 + tid;       // 0..2047
        int d = idx >> 4, jc = idx & 15;
        short8 v;
#pragma unroll
        for (int k = 0; k < 8; ++k) v[k] = lC[(jc * 8 + k) * 132 + d];
        *(short8a*)&vt[((size_t)(bkv * 128 + d)) * 1024 + posBase + jc * 8] = v;
      }
    }
  } else {
#pragma unroll
    for (int mt = 0; mt < 4; ++mt)
#pragma unroll
      for (int nt = 0; nt < 4; ++nt) {
        int row = m0 + wm + mt * 16 + quad * 4;
        int col = n0 + wn + nt * 16 + l16;
        float4_ v = acc[mt][nt];
        float* Cf = (float*)Cv;
#pragma unroll
        for (int r = 0; r < 4; r++) Cf[(size_t)(row + r) * N + col] = v[r];
      }
  }
}

// ---------- 3. GQA causal flash attention (no-max softmax; 128-row Q tiles) ----------
// grid (64 = b*16+h, 8 qtiles reversed), 256 threads = 4 waves x (2 groups x 16 q-rows)
__global__ __launch_bounds__(256, 2)
void flash(const short* __restrict__ qkv, const short* __restrict__ vt,
           const float* __restrict__ head_scale, short* __restrict__ attn) {
  __shared__ alignas(16) short lK[64 * 128];   // [krow][d-chunk swizzled]
  __shared__ alignas(16) short lV[128 * 64];   // [d][krow-chunk swizzled]
  __shared__ alignas(16) short lP[4][32 * 72]; // per-wave P (32 rows), padded stride 72
  const int tid = threadIdx.x, wave = tid >> 6, lane = tid & 63;
  const int quad = lane >> 4, l16 = lane & 15;
  const int bh = blockIdx.x, b = bh >> 4, h = bh & 15, kv = h >> 2;
  const int qt = 7 - blockIdx.y;               // heavy blocks first
  const int base_w = qt * 128 + wave * 32;     // wave's first q-row
  short8 qf[2][4];
#pragma unroll
  for (int g = 0; g < 2; g++) {
    int qrow = base_w + g * 16 + l16;
    const short* qp = qkv + (size_t)(b * 1024 + qrow) * 3072 + h * 128;
#pragma unroll
    for (int kc = 0; kc < 4; kc++) qf[g][kc] = *(const short8a*)(qp + kc * 32 + quad * 8);
  }
  float4_ O[2][8];
#pragma unroll
  for (int g = 0; g < 2; g++)
#pragma unroll
    for (int i = 0; i < 8; i++) O[g][i] = (float4_){0.f, 0.f, 0.f, 0.f};
  float rsacc[2][4] = {{0.f, 0.f, 0.f, 0.f}, {0.f, 0.f, 0.f, 0.f}};
  const size_t kbase = (size_t)(b * 1024) * 3072 + 2048 + kv * 128;
  const size_t vbase = (size_t)((b * 4 + kv) * 128) * 1024;
  const int slot16 = lane & 15, rr4 = lane >> 4;
  const int slot8 = lane & 7, dr8 = lane >> 3;
  const int nkt = 2 * qt + 2;
  for (int kt = 0; kt < nkt; ++kt) {
    __syncthreads();
#pragma unroll
    for (int cc = 0; cc < 4; ++cc) {           // K tile: 64 rows x 128 d
      int rb = wave * 16 + cc * 4;
      int r = rb + rr4;
      int c = slot16 ^ (r & 15);
      async_copy16(&lK[rb * 128], qkv + kbase + (size_t)(kt * 64 + r) * 3072 + c * 8);
    }
#pragma unroll
    for (int cc = 0; cc < 4; ++cc) {           // V tile: 128 d x 64 rows
      int db = wave * 32 + cc * 8;
      int d = db + dr8;
      int c = slot8 ^ (d & 7);
      async_copy16(&lV[db * 64], vt + vbase + (size_t)d * 1024 + kt * 64 + c * 8);
    }
    __syncthreads();
    if (kt * 64 > base_w + 31) continue;       // wave fully below diagonal (uniform)
    // S = Q K^T, both groups share kf
    float4_ S[2][4];
#pragma unroll
    for (int st = 0; st < 4; ++st) {
      float4_ s0 = (float4_){0.f, 0.f, 0.f, 0.f}, s1 = s0;
      int kr = st * 16 + l16;
#pragma unroll
      for (int kc = 0; kc < 4; ++kc) {
        int c = kc * 4 + quad;
        short8 kf = *(const short8a*)&lK[kr * 128 + (c ^ (kr & 15)) * 8];
        s0 = __builtin_amdgcn_mfma_f32_16x16x32_bf16(qf[0][kc], kf, s0, 0, 0, 0);
        s1 = __builtin_amdgcn_mfma_f32_16x16x32_bf16(qf[1][kc], kf, s1, 0, 0, 0);
      }
      S[0][st] = s0; S[1][st] = s1;
    }
    // causal mask + exp + P store
#pragma unroll
    for (int g = 0; g < 2; g++) {
      int gbase = base_w + g * 16;
      if (kt * 64 + 63 > gbase) {
#pragma unroll
        for (int st = 0; st < 4; ++st)
#pragma unroll
          for (int r = 0; r < 4; r++)
            if (kt * 64 + st * 16 + l16 > gbase + quad * 4 + r) S[g][st][r] = -1e30f;
      }
#pragma unroll
      for (int st = 0; st < 4; ++st)
#pragma unroll
        for (int r = 0; r < 4; r++) {
          float pv = __expf(S[g][st][r]);
          rsacc[g][r] += pv;
          lP[wave][(g * 16 + quad * 4 + r) * 72 + st * 16 + l16] = f2b(pv);
        }
    }
    short8 pf[2][2];
#pragma unroll
    for (int g = 0; g < 2; g++)
#pragma unroll
      for (int kc2 = 0; kc2 < 2; kc2++)
        pf[g][kc2] = *(const short8a*)&lP[wave][(g * 16 + l16) * 72 + kc2 * 32 + quad * 8];
#pragma unroll
    for (int dt = 0; dt < 8; ++dt) {
      int d = dt * 16 + l16;
#pragma unroll
      for (int kc2 = 0; kc2 < 2; kc2++) {
        int c = kc2 * 4 + quad;
        short8 vf = *(const short8a*)&lV[d * 64 + (c ^ (d & 7)) * 8];
        O[0][dt] = __builtin_amdgcn_mfma_f32_16x16x32_bf16(pf[0][kc2], vf, O[0][dt], 0, 0, 0);
        O[1][dt] = __builtin_amdgcn_mfma_f32_16x16x32_bf16(pf[1][kc2], vf, O[1][dt], 0, 0, 0);
      }
    }
  }
  float hs = head_scale[h];
#pragma unroll
  for (int g = 0; g < 2; g++) {
    float l_i[4];
#pragma unroll
    for (int r = 0; r < 4; r++) {
      float rs = rsacc[g][r];
#pragma unroll
      for (int off = 8; off; off >>= 1) rs += __shfl_xor(rs, off, 64);
      l_i[r] = rs;
    }
    int qrow = base_w + g * 16 + quad * 4;
#pragma unroll
    for (int dt = 0; dt < 8; ++dt) {
      int col = h * 128 + dt * 16 + l16;
#pragma unroll
      for (int r = 0; r < 4; r++) {
        float o = O[g][dt][r] * (hs / l_i[r]);
        attn[(size_t)(b * 1024 + qrow + r) * 2048 + col] = f2b(o);
      }
    }
  }
}

// ---------- launch ----------
extern "C" void kernel_launch(void* const* d_in, const int* in_sizes, int n_in,
                              void* d_out, int out_size, void* d_ws, size_t ws_size,
                              hipStream_t stream) {
  const float* x  = (const float*)d_in[0];
  const float* Wq = (const float*)d_in[1];
  const float* Wk = (const float*)d_in[2];
  const float* Wv = (const float*)d_in[3];
  const float* Wo = (const float*)d_in[4];
  const float* hs = (const float*)d_in[5];
  float* out = (float*)d_out;
  char* ws = (char*)d_ws;
  // ws layout (64 MB total)
  short* xb    = (short*)(ws);                  // 16 MB  [4096][2048]   (reused as attn)
  short* wqkvt = (short*)(ws + 16777216);       // 12 MB  [3072][2048]
  short* wot   = (short*)(ws + 29360128);       //  8 MB  [2048][2048]
  short* qkv   = (short*)(ws + 37748736);       // 24 MB  [4096][3072] (V cols unused)
  short* vt    = (short*)(ws + 62914560);       //  4 MB  [2048][1024]
  short* attn  = xb;                            // alias: xb dead after GEMM1
  // rope table lives in d_out's tail: d_out (32 MB fp32) is dead until GEMM2 fully overwrites it
  float* rtab  = out + 8257536;                 // 512 KB = 131072 floats

  prep<<<11008, 256, 0, stream>>>(x, Wq, Wk, Wv, Wo, xb, wqkvt, wot, rtab);
  gemm_bt<1><<<dim3(32, 24), 256, 0, stream>>>(xb, wqkvt, (void*)qkv, rtab, vt, 4096, 3072, 2048);
  flash<<<dim3(64, 8), 256, 0, stream>>>(qkv, vt, hs, attn);
  gemm_bt<0><<<dim3(32, 16), 256, 0, stream>>>(attn, wot, (void*)out, nullptr, nullptr, 4096, 2048, 2048);
}

// Round 5
// 252.018 us; speedup vs baseline: 1.0141x; 1.0135x over previous
//
#include <hip/hip_runtime.h>

// ---------- types ----------
typedef __attribute__((ext_vector_type(8))) short short8;
typedef __attribute__((ext_vector_type(8), may_alias)) short short8a;
typedef __attribute__((ext_vector_type(4))) short short4a_ __attribute__((may_alias));
typedef __attribute__((ext_vector_type(2), may_alias)) short short2a;
typedef __attribute__((ext_vector_type(4))) float float4_;
typedef __attribute__((ext_vector_type(4), may_alias)) float float4a;
typedef __attribute__((ext_vector_type(2), may_alias)) float float2a;

__device__ __forceinline__ float b2f(short h) {
  unsigned int u = ((unsigned int)(unsigned short)h) << 16;
  return __builtin_bit_cast(float, u);
}
__device__ __forceinline__ short f2b(float f) {
  unsigned int u = __builtin_bit_cast(unsigned int, f);
  u += 0x7fffu + ((u >> 16) & 1u);   // RNE
  return (short)(unsigned short)(u >> 16);
}

#define GLOBAL_AS __attribute__((address_space(1)))
#define LDS_AS    __attribute__((address_space(3)))
__device__ __forceinline__ void async_copy16(void* lds, const void* g) {
  __builtin_amdgcn_global_load_lds((GLOBAL_AS const void*)g, (LDS_AS void*)lds, 16, 0, 0);
}

// ---------- 1. fused prep: x->bf16, Wq|Wk|Wv transpose (q-scale folded), Wo transpose, rope table ----------
// grid: [0,1536) wqkv tiles, [1536,2560) wo tiles, [2560,10752) cvt blocks, [10752,11008) rope table
__global__ __launch_bounds__(256) void prep(const float* __restrict__ x,
                                            const float* __restrict__ Wq,
                                            const float* __restrict__ Wk,
                                            const float* __restrict__ Wv,
                                            const float* __restrict__ Wo,
                                            short* __restrict__ xb,
                                            short* __restrict__ wqkvt,
                                            short* __restrict__ wot,
                                            float* __restrict__ rtab) {
  __shared__ float tile[64][65];
  int bid = blockIdx.x;
  if (bid < 1536) {                     // Wq|Wk|Wv -> [3072][2048] bf16 (B^T)
    int k0 = (bid & 31) * 64, n0 = (bid >> 5) * 64;
    for (int idx = threadIdx.x; idx < 4096; idx += 256) {
      int r = idx >> 6, cc = idx & 63;
      int n = n0 + cc;
      float v;
      if (n < 2048)      v = Wq[(size_t)(k0 + r) * 2048 + n] * 0.08838834764831845f; // fold 1/sqrt(128)
      else if (n < 2560) v = Wk[(size_t)(k0 + r) * 512 + (n - 2048)];
      else               v = Wv[(size_t)(k0 + r) * 512 + (n - 2560)];
      tile[r][cc] = v;
    }
    __syncthreads();
    for (int idx = threadIdx.x; idx < 4096; idx += 256) {
      int r = idx >> 6, cc = idx & 63;
      wqkvt[(size_t)(n0 + r) * 2048 + k0 + cc] = f2b(tile[cc][r]);
    }
  } else if (bid < 2560) {              // Wo -> [2048][2048] bf16 (B^T)
    int t = bid - 1536;
    int k0 = (t & 31) * 64, n0 = (t >> 5) * 64;
    for (int idx = threadIdx.x; idx < 4096; idx += 256) {
      int r = idx >> 6, cc = idx & 63;
      tile[r][cc] = Wo[(size_t)(k0 + r) * 2048 + n0 + cc];
    }
    __syncthreads();
    for (int idx = threadIdx.x; idx < 4096; idx += 256) {
      int r = idx >> 6, cc = idx & 63;
      wot[(size_t)(n0 + r) * 2048 + k0 + cc] = f2b(tile[cc][r]);
    }
  } else if (bid < 10752) {             // x fp32 -> bf16
    int i = (bid - 2560) * 256 + threadIdx.x;
    float4a v = ((const float4a*)x)[i];
    short4a_ o;
    o.x = f2b(v.x); o.y = f2b(v.y); o.z = f2b(v.z); o.w = f2b(v.w);
    ((short4a_*)xb)[i] = o;
  } else {                              // rope table: rtab[(pos*64+i)*2] = {cos, sin}
    int idx = (bid - 10752) * 256 + threadIdx.x;   // 0..65535
    int pos = idx >> 6, i = idx & 63;
    float inv = exp2f((float)i * -0.20762050593478f);  // 10000^(-2i/128)
    float s, c;
    sincosf((float)pos * inv, &s, &c);
    float2a cs; cs.x = c; cs.y = s;
    ((float2a*)rtab)[idx] = cs;
  }
}

// ---------- 2a. GEMM1 (proven round-0 structure, 891 TF = m97-structure ceiling) ----------
// 128x128 tile, BK=64, 4 waves, 2-phase K-loop, global_load_lds(16B), XOR chunk swizzle.
// Fused epilogue: n0<2560 -> RoPE -> qkv; else transposed V -> vt.
__global__ __launch_bounds__(256, 2)
void gemm_rope(const short* __restrict__ A, const short* __restrict__ B,
               short* __restrict__ Cb, const float* __restrict__ rtab,
               short* __restrict__ vt, int M, int N, int K) {
  __shared__ alignas(16) short lsm[16896];
  short* lA = lsm;
  short* lB = lsm + 8192;
  const int tid = threadIdx.x;
  const int wave = tid >> 6, lane = tid & 63;
  const int quad = lane >> 4, l16 = lane & 15;
  const int m0 = blockIdx.x * 128, n0 = blockIdx.y * 128;
  const int wm = (wave >> 1) * 64, wn = (wave & 1) * 64;
  float4_ acc[4][4];
#pragma unroll
  for (int i = 0; i < 4; i++)
#pragma unroll
    for (int j = 0; j < 4; j++) acc[i][j] = (float4_){0.f, 0.f, 0.f, 0.f};
  const int nK = K >> 6;
  const int srow = lane >> 3, slot = lane & 7;
  for (int kt = 0; kt < nK; ++kt) {
    __syncthreads();
#pragma unroll
    for (int cth = 0; cth < 4; ++cth) {
      int rb = wave * 32 + cth * 8;
      int r = rb + srow;
      int c = slot ^ (r & 7);
      async_copy16(&lA[rb * 64], A + (size_t)(m0 + r) * K + kt * 64 + c * 8);
      async_copy16(&lB[rb * 64], B + (size_t)(n0 + r) * K + kt * 64 + c * 8);
    }
    __syncthreads();
#pragma unroll
    for (int kc = 0; kc < 2; ++kc) {
      short8 af[4], bf[4];
      int cch = kc * 4 + quad;
#pragma unroll
      for (int mt = 0; mt < 4; ++mt) {
        int ar = wm + mt * 16 + l16;
        af[mt] = *(const short8a*)&lA[ar * 64 + (cch ^ (ar & 7)) * 8];
      }
#pragma unroll
      for (int nt = 0; nt < 4; ++nt) {
        int br = wn + nt * 16 + l16;
        bf[nt] = *(const short8a*)&lB[br * 64 + (cch ^ (br & 7)) * 8];
      }
#pragma unroll
      for (int mt = 0; mt < 4; ++mt)
#pragma unroll
        for (int nt = 0; nt < 4; ++nt)
          acc[mt][nt] = __builtin_amdgcn_mfma_f32_16x16x32_bf16(af[mt], bf[nt], acc[mt][nt], 0, 0, 0);
    }
  }
  const bool isRope = (n0 < 2560);    // block-uniform
  __syncthreads();                    // staging LDS now dead
  short* lC = lsm;                    // [128][132] bf16
  const int posBase = m0 & 1023;
  float4a tv[16];
  if (isRope) {                       // hoist table loads: latency hidden behind lC writes + barrier
#pragma unroll
    for (int it = 0; it < 16; ++it) {
      int idx = it * 256 + tid;
      int row = idx >> 5, c2 = (idx & 31) * 2;
      tv[it] = *(const float4a*)&rtab[((size_t)(posBase + row) * 64 + c2) * 2];
    }
  }
#pragma unroll
  for (int mt = 0; mt < 4; ++mt)
#pragma unroll
    for (int nt = 0; nt < 4; ++nt)
#pragma unroll
      for (int r = 0; r < 4; r++)
        lC[(wm + mt * 16 + quad * 4 + r) * 132 + wn + nt * 16 + l16] = f2b(acc[mt][nt][r]);
  __syncthreads();
  if (isRope) {
#pragma unroll
    for (int it = 0; it < 16; ++it) {
      int idx = it * 256 + tid;       // 0..4095
      int row = idx >> 5;             // 0..127
      int c2 = (idx & 31) * 2;        // pair indices c2, c2+1 (in [0,64))
      short2a t1 = *(const short2a*)&lC[row * 132 + c2];
      short2a t2 = *(const short2a*)&lC[row * 132 + c2 + 64];
      float t1a = b2f(t1.x), t1b = b2f(t1.y);
      float t2a = b2f(t2.x), t2b = b2f(t2.y);
      float4a t = tv[it];             // ca,sa,cb,sb
      short2a o1, o2;
      o1.x = f2b(t1a * t.x - t2a * t.y); o1.y = f2b(t1b * t.z - t2b * t.w);
      o2.x = f2b(t2a * t.x + t1a * t.y); o2.y = f2b(t2b * t.z + t1b * t.w);
      size_t base = (size_t)(m0 + row) * N + n0;
      *(short2a*)&Cb[base + c2] = o1;
      *(short2a*)&Cb[base + c2 + 64] = o2;
    }
  } else {
    // V block: transposed store into vt[(b*4+kv)*128+d][seq]
    const int bkv = (m0 >> 10) * 4 + ((n0 - 2560) >> 7);
#pragma unroll
    for (int it = 0; it < 8; ++it) {
      int idx = it * 256 + tid;       // 0..2047
      int d = idx >> 4, jc = idx & 15;
      short8 v;
#pragma unroll
      for (int k = 0; k < 8; ++k) v[k] = lC[(jc * 8 + k) * 132 + d];
      *(short8a*)&vt[((size_t)(bkv * 128 + d)) * 1024 + posBase + jc * 8] = v;
    }
  }
}

// ---------- 2b. GEMM2 (round-2 proven: BM=128 x BN=256, 4-phase counted-vmcnt) ----------
// 8 waves (2M x 4N; per-wave 64x64), grid 32x8 = 256 blocks (100% fill), LDS 96 KiB.
// Phase = consumption group g=(tile,kh): 16 MFMA, stage group g+3 (3 loads), 2 barriers;
// at phase end vmcnt(6) retires g+1 (issued ~2.5 phases earlier); never vmcnt(0) mid-loop.
#define FENCE() __builtin_amdgcn_sched_barrier(0)

template <int N_>
__device__ __forceinline__ void waitv() {
  if constexpr (N_ == 6)      asm volatile("s_waitcnt vmcnt(6)" ::: "memory");
  else if constexpr (N_ == 3) asm volatile("s_waitcnt vmcnt(3)" ::: "memory");
  else                        asm volatile("s_waitcnt vmcnt(0)" ::: "memory");
}

#define STG2(P_, KH_, T_, PART_)                                                   \
  do { if ((T_) < nK) {                                                            \
    const size_t co_ = (size_t)(T_) * 64 + (KH_) * 32;                             \
    if ((PART_) == 0) {                                                            \
      async_copy16(&lsm[(P_) * 24576 + (KH_) * 4096 + wave * 512], Asrc + co_);    \
      async_copy16(&lsm[(P_) * 24576 + 8192 + (KH_) * 8192 + wave * 512],          \
                   Bsrc + co_);                                                    \
    } else {                                                                       \
      async_copy16(&lsm[(P_) * 24576 + 8192 + (KH_) * 8192 + 4096 + wave * 512],   \
                   Bsrc + 128 * (size_t)K + co_);                                  \
    }                                                                              \
  } } while (0)

#define WAITG2(G_)                                                                 \
  do { int rem_ = 2 * nK - 2 - (G_);                                               \
    if (rem_ >= 2) waitv<6>();                                                     \
    else if (rem_ == 1) waitv<3>();                                                \
    else waitv<0>(); } while (0)

#define PHASED2(P_, KK_, STAGE0, STAGE1, ENDW)                                     \
  {                                                                                \
    short8 af[4];                                                                  \
    _Pragma("unroll") for (int mi = 0; mi < 4; ++mi)                               \
      af[mi] = *(const short8a*)&lsm[(P_) * 24576 + (KK_) * 4096 + aoff[mi]];      \
    short8 bf[4];                                                                  \
    _Pragma("unroll") for (int ni = 0; ni < 4; ++ni)                               \
      bf[ni] = *(const short8a*)&lsm[(P_) * 24576 + 8192 + (KK_) * 8192 +          \
                                     boff[ni]];                                    \
    STAGE0; STAGE1;                                                                \
    FENCE();                                                                       \
    __builtin_amdgcn_s_barrier();                                                  \
    FENCE();                                                                       \
    __builtin_amdgcn_s_setprio(1);                                                 \
    _Pragma("unroll") for (int mi = 0; mi < 4; ++mi)                               \
      _Pragma("unroll") for (int ni = 0; ni < 4; ++ni)                             \
        acc[mi][ni] = __builtin_amdgcn_mfma_f32_16x16x32_bf16(                     \
            af[mi], bf[ni], acc[mi][ni], 0, 0, 0);                                 \
    __builtin_amdgcn_s_setprio(0);                                                 \
    FENCE();                                                                       \
    ENDW;                                                                          \
    __builtin_amdgcn_s_barrier();                                                  \
    FENCE();                                                                       \
  }

__global__ __launch_bounds__(512, 2)
void gemm_out(const short* __restrict__ A, const short* __restrict__ B,
              float* __restrict__ Cf, int M, int N, int K) {
  __shared__ alignas(16) short lsm[49152];   // 96 KiB (2 x 24576 shorts)
  const int tid = threadIdx.x;
  const int wave = tid >> 6, lane = tid & 63;
  const int quad = lane >> 4, l16 = lane & 15;
  const int m0 = blockIdx.x * 128, n0 = blockIdx.y * 256;
  const int wm = (wave >> 2) * 64, wn = (wave & 3) * 64;
  const int nK = K >> 6;               // even, >= 2

  int aoff[4], boff[4];
#pragma unroll
  for (int j = 0; j < 4; ++j) {
    int r = wm + j * 16 + l16;
    aoff[j] = r * 32 + (quad ^ ((r >> 1) & 3)) * 8;
  }
#pragma unroll
  for (int ni = 0; ni < 4; ++ni) {
    int r = wn + ni * 16 + l16;
    boff[ni] = r * 32 + (quad ^ ((r >> 1) & 3)) * 8;
  }
  const int r0 = tid >> 2;
  const int qq = (tid & 3) ^ ((r0 >> 1) & 3);   // invariant under row+128
  const short* Asrc = A + (size_t)(m0 + r0) * K + qq * 8;
  const short* Bsrc = B + (size_t)(n0 + r0) * K + qq * 8;

  float4_ acc[4][4];
#pragma unroll
  for (int i = 0; i < 4; i++)
#pragma unroll
    for (int j = 0; j < 4; j++) acc[i][j] = (float4_){0.f, 0.f, 0.f, 0.f};

  // prologue: stage groups 0,1,2; retire group 0 (keep 1,2 in flight)
  STG2(0, 0, 0, 0); STG2(0, 0, 0, 1);
  STG2(0, 1, 0, 0); STG2(0, 1, 0, 1);
  STG2(1, 0, 1, 0); STG2(1, 0, 1, 1);
  FENCE();
  waitv<6>();
  __builtin_amdgcn_s_barrier();
  FENCE();

  for (int t = 0; t < nK; t += 2) {
    PHASED2(0, 0, STG2(1, 1, t + 1, 0), STG2(1, 1, t + 1, 1), WAITG2(2 * t));
    PHASED2(0, 1, STG2(0, 0, t + 2, 0), STG2(0, 0, t + 2, 1), WAITG2(2 * t + 1));
    PHASED2(1, 0, STG2(0, 1, t + 2, 0), STG2(0, 1, t + 2, 1), WAITG2(2 * t + 2));
    PHASED2(1, 1, STG2(1, 0, t + 3, 0), STG2(1, 0, t + 3, 1), WAITG2(2 * t + 3));
  }

#pragma unroll
  for (int mt = 0; mt < 4; ++mt)
#pragma unroll
    for (int ni = 0; ni < 4; ++ni) {
      int row = m0 + wm + mt * 16 + quad * 4;
      int col = n0 + wn + ni * 16 + l16;
      float4_ v = acc[mt][ni];
#pragma unroll
      for (int r = 0; r < 4; r++) Cf[(size_t)(row + r) * N + col] = v[r];
    }
}

// ---------- 3. GQA causal flash attention (no-max softmax; 128-row Q tiles) ----------
// grid (64 = b*16+h, 8 qtiles reversed), 256 threads = 4 waves x (2 groups x 16 q-rows)
__global__ __launch_bounds__(256, 2)
void flash(const short* __restrict__ qkv, const short* __restrict__ vt,
           const float* __restrict__ head_scale, short* __restrict__ attn) {
  __shared__ alignas(16) short lK[64 * 128];   // [krow][d-chunk swizzled]
  __shared__ alignas(16) short lV[128 * 64];   // [d][krow-chunk swizzled]
  __shared__ alignas(16) short lP[4][32 * 72]; // per-wave P (32 rows), padded stride 72
  const int tid = threadIdx.x, wave = tid >> 6, lane = tid & 63;
  const int quad = lane >> 4, l16 = lane & 15;
  const int bh = blockIdx.x, b = bh >> 4, h = bh & 15, kv = h >> 2;
  const int qt = 7 - blockIdx.y;               // heavy blocks first
  const int base_w = qt * 128 + wave * 32;     // wave's first q-row
  short8 qf[2][4];
#pragma unroll
  for (int g = 0; g < 2; g++) {
    int qrow = base_w + g * 16 + l16;
    const short* qp = qkv + (size_t)(b * 1024 + qrow) * 3072 + h * 128;
#pragma unroll
    for (int kc = 0; kc < 4; kc++) qf[g][kc] = *(const short8a*)(qp + kc * 32 + quad * 8);
  }
  float4_ O[2][8];
#pragma unroll
  for (int g = 0; g < 2; g++)
#pragma unroll
    for (int i = 0; i < 8; i++) O[g][i] = (float4_){0.f, 0.f, 0.f, 0.f};
  float rsacc[2][4] = {{0.f, 0.f, 0.f, 0.f}, {0.f, 0.f, 0.f, 0.f}};
  const size_t kbase = (size_t)(b * 1024) * 3072 + 2048 + kv * 128;
  const size_t vbase = (size_t)((b * 4 + kv) * 128) * 1024;
  const int slot16 = lane & 15, rr4 = lane >> 4;
  const int slot8 = lane & 7, dr8 = lane >> 3;
  const int nkt = 2 * qt + 2;
  for (int kt = 0; kt < nkt; ++kt) {
    __syncthreads();
#pragma unroll
    for (int cc = 0; cc < 4; ++cc) {           // K tile: 64 rows x 128 d
      int rb = wave * 16 + cc * 4;
      int r = rb + rr4;
      int c = slot16 ^ (r & 15);
      async_copy16(&lK[rb * 128], qkv + kbase + (size_t)(kt * 64 + r) * 3072 + c * 8);
    }
#pragma unroll
    for (int cc = 0; cc < 4; ++cc) {           // V tile: 128 d x 64 rows
      int db = wave * 32 + cc * 8;
      int d = db + dr8;
      int c = slot8 ^ (d & 7);
      async_copy16(&lV[db * 64], vt + vbase + (size_t)d * 1024 + kt * 64 + c * 8);
    }
    __syncthreads();
    if (kt * 64 > base_w + 31) continue;       // wave fully below diagonal (uniform)
    // S = Q K^T, both groups share kf
    float4_ S[2][4];
#pragma unroll
    for (int st = 0; st < 4; ++st) {
      float4_ s0 = (float4_){0.f, 0.f, 0.f, 0.f}, s1 = s0;
      int kr = st * 16 + l16;
#pragma unroll
      for (int kc = 0; kc < 4; ++kc) {
        int c = kc * 4 + quad;
        short8 kf = *(const short8a*)&lK[kr * 128 + (c ^ (kr & 15)) * 8];
        s0 = __builtin_amdgcn_mfma_f32_16x16x32_bf16(qf[0][kc], kf, s0, 0, 0, 0);
        s1 = __builtin_amdgcn_mfma_f32_16x16x32_bf16(qf[1][kc], kf, s1, 0, 0, 0);
      }
      S[0][st] = s0; S[1][st] = s1;
    }
    // causal mask + exp + P store
#pragma unroll
    for (int g = 0; g < 2; g++) {
      int gbase = base_w + g * 16;
      if (kt * 64 + 63 > gbase) {
#pragma unroll
        for (int st = 0; st < 4; ++st)
#pragma unroll
          for (int r = 0; r < 4; r++)
            if (kt * 64 + st * 16 + l16 > gbase + quad * 4 + r) S[g][st][r] = -1e30f;
      }
#pragma unroll
      for (int st = 0; st < 4; ++st)
#pragma unroll
        for (int r = 0; r < 4; r++) {
          float pv = __expf(S[g][st][r]);
          rsacc[g][r] += pv;
          lP[wave][(g * 16 + quad * 4 + r) * 72 + st * 16 + l16] = f2b(pv);
        }
    }
    short8 pf[2][2];
#pragma unroll
    for (int g = 0; g < 2; g++)
#pragma unroll
      for (int kc2 = 0; kc2 < 2; kc2++)
        pf[g][kc2] = *(const short8a*)&lP[wave][(g * 16 + l16) * 72 + kc2 * 32 + quad * 8];
#pragma unroll
    for (int dt = 0; dt < 8; ++dt) {
      int d = dt * 16 + l16;
#pragma unroll
      for (int kc2 = 0; kc2 < 2; kc2++) {
        int c = kc2 * 4 + quad;
        short8 vf = *(const short8a*)&lV[d * 64 + (c ^ (d & 7)) * 8];
        O[0][dt] = __builtin_amdgcn_mfma_f32_16x16x32_bf16(pf[0][kc2], vf, O[0][dt], 0, 0, 0);
        O[1][dt] = __builtin_amdgcn_mfma_f32_16x16x32_bf16(pf[1][kc2], vf, O[1][dt], 0, 0, 0);
      }
    }
  }
  float hs = head_scale[h];
#pragma unroll
  for (int g = 0; g < 2; g++) {
    float l_i[4];
#pragma unroll
    for (int r = 0; r < 4; r++) {
      float rs = rsacc[g][r];
#pragma unroll
      for (int off = 8; off; off >>= 1) rs += __shfl_xor(rs, off, 64);
      l_i[r] = rs;
    }
    int qrow = base_w + g * 16 + quad * 4;
#pragma unroll
    for (int dt = 0; dt < 8; ++dt) {
      int col = h * 128 + dt * 16 + l16;
#pragma unroll
      for (int r = 0; r < 4; r++) {
        float o = O[g][dt][r] * (hs / l_i[r]);
        attn[(size_t)(b * 1024 + qrow + r) * 2048 + col] = f2b(o);
      }
    }
  }
}

// ---------- launch ----------
extern "C" void kernel_launch(void* const* d_in, const int* in_sizes, int n_in,
                              void* d_out, int out_size, void* d_ws, size_t ws_size,
                              hipStream_t stream) {
  const float* x  = (const float*)d_in[0];
  const float* Wq = (const float*)d_in[1];
  const float* Wk = (const float*)d_in[2];
  const float* Wv = (const float*)d_in[3];
  const float* Wo = (const float*)d_in[4];
  const float* hs = (const float*)d_in[5];
  float* out = (float*)d_out;
  char* ws = (char*)d_ws;
  // ws layout (64 MB total)
  short* xb    = (short*)(ws);                  // 16 MB  [4096][2048]   (reused as attn)
  short* wqkvt = (short*)(ws + 16777216);       // 12 MB  [3072][2048]
  short* wot   = (short*)(ws + 29360128);       //  8 MB  [2048][2048]
  short* qkv   = (short*)(ws + 37748736);       // 24 MB  [4096][3072] (V cols unused)
  short* vt    = (short*)(ws + 62914560);       //  4 MB  [2048][1024]
  short* attn  = xb;                            // alias: xb dead after GEMM1
  // rope table lives in d_out's tail: d_out (32 MB fp32) is dead until GEMM2 fully overwrites it
  float* rtab  = out + 8257536;                 // 512 KB = 131072 floats

  prep<<<11008, 256, 0, stream>>>(x, Wq, Wk, Wv, Wo, xb, wqkvt, wot, rtab);
  gemm_rope<<<dim3(32, 24), 256, 0, stream>>>(xb, wqkvt, qkv, rtab, vt, 4096, 3072, 2048);
  flash<<<dim3(64, 8), 256, 0, stream>>>(qkv, vt, hs, attn);
  gemm_out<<<dim3(32, 8), 512, 0, stream>>>(attn, wot, out, 4096, 2048, 2048);
}

// Round 6
// 248.085 us; speedup vs baseline: 1.0302x; 1.0159x over previous
//
#include <hip/hip_runtime.h>

// ---------- types ----------
typedef __attribute__((ext_vector_type(8))) short short8;
typedef __attribute__((ext_vector_type(8), may_alias)) short short8a;
typedef __attribute__((ext_vector_type(4))) short short4a_ __attribute__((may_alias));
typedef __attribute__((ext_vector_type(2), may_alias)) short short2a;
typedef __attribute__((ext_vector_type(4))) float float4_;
typedef __attribute__((ext_vector_type(4), may_alias)) float float4a;
typedef __attribute__((ext_vector_type(2), may_alias)) float float2a;

__device__ __forceinline__ float b2f(short h) {
  unsigned int u = ((unsigned int)(unsigned short)h) << 16;
  return __builtin_bit_cast(float, u);
}
__device__ __forceinline__ short f2b(float f) {
  unsigned int u = __builtin_bit_cast(unsigned int, f);
  u += 0x7fffu + ((u >> 16) & 1u);   // RNE
  return (short)(unsigned short)(u >> 16);
}

#define GLOBAL_AS __attribute__((address_space(1)))
#define LDS_AS    __attribute__((address_space(3)))
__device__ __forceinline__ void async_copy16(void* lds, const void* g) {
  __builtin_amdgcn_global_load_lds((GLOBAL_AS const void*)g, (LDS_AS void*)lds, 16, 0, 0);
}

// ---------- 1. fused prep: x->bf16, Wq|Wk|Wv transpose (q-scale folded), Wo transpose, rope table ----------
// grid: [0,1536) wqkv tiles, [1536,2560) wo tiles, [2560,10752) cvt blocks, [10752,11008) rope table
__global__ __launch_bounds__(256) void prep(const float* __restrict__ x,
                                            const float* __restrict__ Wq,
                                            const float* __restrict__ Wk,
                                            const float* __restrict__ Wv,
                                            const float* __restrict__ Wo,
                                            short* __restrict__ xb,
                                            short* __restrict__ wqkvt,
                                            short* __restrict__ wot,
                                            float* __restrict__ rtab) {
  __shared__ float tile[64][65];
  int bid = blockIdx.x;
  if (bid < 1536) {                     // Wq|Wk|Wv -> [3072][2048] bf16 (B^T)
    int k0 = (bid & 31) * 64, n0 = (bid >> 5) * 64;
    for (int idx = threadIdx.x; idx < 4096; idx += 256) {
      int r = idx >> 6, cc = idx & 63;
      int n = n0 + cc;
      float v;
      if (n < 2048)      v = Wq[(size_t)(k0 + r) * 2048 + n] * 0.08838834764831845f; // fold 1/sqrt(128)
      else if (n < 2560) v = Wk[(size_t)(k0 + r) * 512 + (n - 2048)];
      else               v = Wv[(size_t)(k0 + r) * 512 + (n - 2560)];
      tile[r][cc] = v;
    }
    __syncthreads();
    for (int idx = threadIdx.x; idx < 4096; idx += 256) {
      int r = idx >> 6, cc = idx & 63;
      wqkvt[(size_t)(n0 + r) * 2048 + k0 + cc] = f2b(tile[cc][r]);
    }
  } else if (bid < 2560) {              // Wo -> [2048][2048] bf16 (B^T)
    int t = bid - 1536;
    int k0 = (t & 31) * 64, n0 = (t >> 5) * 64;
    for (int idx = threadIdx.x; idx < 4096; idx += 256) {
      int r = idx >> 6, cc = idx & 63;
      tile[r][cc] = Wo[(size_t)(k0 + r) * 2048 + n0 + cc];
    }
    __syncthreads();
    for (int idx = threadIdx.x; idx < 4096; idx += 256) {
      int r = idx >> 6, cc = idx & 63;
      wot[(size_t)(n0 + r) * 2048 + k0 + cc] = f2b(tile[cc][r]);
    }
  } else if (bid < 10752) {             // x fp32 -> bf16
    int i = (bid - 2560) * 256 + threadIdx.x;
    float4a v = ((const float4a*)x)[i];
    short4a_ o;
    o.x = f2b(v.x); o.y = f2b(v.y); o.z = f2b(v.z); o.w = f2b(v.w);
    ((short4a_*)xb)[i] = o;
  } else {                              // rope table: rtab[(pos*64+i)*2] = {cos, sin}
    int idx = (bid - 10752) * 256 + threadIdx.x;   // 0..65535
    int pos = idx >> 6, i = idx & 63;
    float inv = exp2f((float)i * -0.20762050593478f);  // 10000^(-2i/128)
    float s, c;
    sincosf((float)pos * inv, &s, &c);
    float2a cs; cs.x = c; cs.y = s;
    ((float2a*)rtab)[idx] = cs;
  }
}

// ---------- 2a. GEMM1 (proven round-0 structure, 891 TF = m97-structure ceiling) ----------
// 128x128 tile, BK=64, 4 waves, 2-phase K-loop, global_load_lds(16B), XOR chunk swizzle.
// Fused epilogue: n0<2560 -> RoPE -> qkv; else transposed V -> vt.
__global__ __launch_bounds__(256, 2)
void gemm_rope(const short* __restrict__ A, const short* __restrict__ B,
               short* __restrict__ Cb, const float* __restrict__ rtab,
               short* __restrict__ vt, int M, int N, int K) {
  __shared__ alignas(16) short lsm[16896];
  short* lA = lsm;
  short* lB = lsm + 8192;
  const int tid = threadIdx.x;
  const int wave = tid >> 6, lane = tid & 63;
  const int quad = lane >> 4, l16 = lane & 15;
  const int m0 = blockIdx.x * 128, n0 = blockIdx.y * 128;
  const int wm = (wave >> 1) * 64, wn = (wave & 1) * 64;
  float4_ acc[4][4];
#pragma unroll
  for (int i = 0; i < 4; i++)
#pragma unroll
    for (int j = 0; j < 4; j++) acc[i][j] = (float4_){0.f, 0.f, 0.f, 0.f};
  const int nK = K >> 6;
  const int srow = lane >> 3, slot = lane & 7;
  for (int kt = 0; kt < nK; ++kt) {
    __syncthreads();
#pragma unroll
    for (int cth = 0; cth < 4; ++cth) {
      int rb = wave * 32 + cth * 8;
      int r = rb + srow;
      int c = slot ^ (r & 7);
      async_copy16(&lA[rb * 64], A + (size_t)(m0 + r) * K + kt * 64 + c * 8);
      async_copy16(&lB[rb * 64], B + (size_t)(n0 + r) * K + kt * 64 + c * 8);
    }
    __syncthreads();
#pragma unroll
    for (int kc = 0; kc < 2; ++kc) {
      short8 af[4], bf[4];
      int cch = kc * 4 + quad;
#pragma unroll
      for (int mt = 0; mt < 4; ++mt) {
        int ar = wm + mt * 16 + l16;
        af[mt] = *(const short8a*)&lA[ar * 64 + (cch ^ (ar & 7)) * 8];
      }
#pragma unroll
      for (int nt = 0; nt < 4; ++nt) {
        int br = wn + nt * 16 + l16;
        bf[nt] = *(const short8a*)&lB[br * 64 + (cch ^ (br & 7)) * 8];
      }
#pragma unroll
      for (int mt = 0; mt < 4; ++mt)
#pragma unroll
        for (int nt = 0; nt < 4; ++nt)
          acc[mt][nt] = __builtin_amdgcn_mfma_f32_16x16x32_bf16(af[mt], bf[nt], acc[mt][nt], 0, 0, 0);
    }
  }
  const bool isRope = (n0 < 2560);    // block-uniform
  __syncthreads();                    // staging LDS now dead
  short* lC = lsm;                    // [128][132] bf16
  const int posBase = m0 & 1023;
  float4a tv[16];
  if (isRope) {                       // hoist table loads: latency hidden behind lC writes + barrier
#pragma unroll
    for (int it = 0; it < 16; ++it) {
      int idx = it * 256 + tid;
      int row = idx >> 5, c2 = (idx & 31) * 2;
      tv[it] = *(const float4a*)&rtab[((size_t)(posBase + row) * 64 + c2) * 2];
    }
  }
#pragma unroll
  for (int mt = 0; mt < 4; ++mt)
#pragma unroll
    for (int nt = 0; nt < 4; ++nt)
#pragma unroll
      for (int r = 0; r < 4; r++)
        lC[(wm + mt * 16 + quad * 4 + r) * 132 + wn + nt * 16 + l16] = f2b(acc[mt][nt][r]);
  __syncthreads();
  if (isRope) {
#pragma unroll
    for (int it = 0; it < 16; ++it) {
      int idx = it * 256 + tid;       // 0..4095
      int row = idx >> 5;             // 0..127
      int c2 = (idx & 31) * 2;        // pair indices c2, c2+1 (in [0,64))
      short2a t1 = *(const short2a*)&lC[row * 132 + c2];
      short2a t2 = *(const short2a*)&lC[row * 132 + c2 + 64];
      float t1a = b2f(t1.x), t1b = b2f(t1.y);
      float t2a = b2f(t2.x), t2b = b2f(t2.y);
      float4a t = tv[it];             // ca,sa,cb,sb
      short2a o1, o2;
      o1.x = f2b(t1a * t.x - t2a * t.y); o1.y = f2b(t1b * t.z - t2b * t.w);
      o2.x = f2b(t2a * t.x + t1a * t.y); o2.y = f2b(t2b * t.z + t1b * t.w);
      size_t base = (size_t)(m0 + row) * N + n0;
      *(short2a*)&Cb[base + c2] = o1;
      *(short2a*)&Cb[base + c2 + 64] = o2;
    }
  } else {
    // V block: transposed store into vt[(b*4+kv)*128+d][seq]
    const int bkv = (m0 >> 10) * 4 + ((n0 - 2560) >> 7);
#pragma unroll
    for (int it = 0; it < 8; ++it) {
      int idx = it * 256 + tid;       // 0..2047
      int d = idx >> 4, jc = idx & 15;
      short8 v;
#pragma unroll
      for (int k = 0; k < 8; ++k) v[k] = lC[(jc * 8 + k) * 132 + d];
      *(short8a*)&vt[((size_t)(bkv * 128 + d)) * 1024 + posBase + jc * 8] = v;
    }
  }
}

// ---------- 2b. GEMM2 (round-2 proven: BM=128 x BN=256, 4-phase counted-vmcnt) ----------
// 8 waves (2M x 4N; per-wave 64x64), grid 32x8 = 256 blocks (100% fill), LDS 96 KiB.
// Phase = consumption group g=(tile,kh): 16 MFMA, stage group g+3 (3 loads), 2 barriers;
// at phase end vmcnt(6) retires g+1 (issued ~2.5 phases earlier); never vmcnt(0) mid-loop.
#define FENCE() __builtin_amdgcn_sched_barrier(0)

template <int N_>
__device__ __forceinline__ void waitv() {
  if constexpr (N_ == 6)      asm volatile("s_waitcnt vmcnt(6)" ::: "memory");
  else if constexpr (N_ == 3) asm volatile("s_waitcnt vmcnt(3)" ::: "memory");
  else                        asm volatile("s_waitcnt vmcnt(0)" ::: "memory");
}

#define STG2(P_, KH_, T_, PART_)                                                   \
  do { if ((T_) < nK) {                                                            \
    const size_t co_ = (size_t)(T_) * 64 + (KH_) * 32;                             \
    if ((PART_) == 0) {                                                            \
      async_copy16(&lsm[(P_) * 24576 + (KH_) * 4096 + wave * 512], Asrc + co_);    \
      async_copy16(&lsm[(P_) * 24576 + 8192 + (KH_) * 8192 + wave * 512],          \
                   Bsrc + co_);                                                    \
    } else {                                                                       \
      async_copy16(&lsm[(P_) * 24576 + 8192 + (KH_) * 8192 + 4096 + wave * 512],   \
                   Bsrc + 128 * (size_t)K + co_);                                  \
    }                                                                              \
  } } while (0)

#define WAITG2(G_)                                                                 \
  do { int rem_ = 2 * nK - 2 - (G_);                                               \
    if (rem_ >= 2) waitv<6>();                                                     \
    else if (rem_ == 1) waitv<3>();                                                \
    else waitv<0>(); } while (0)

#define PHASED2(P_, KK_, STAGE0, STAGE1, ENDW)                                     \
  {                                                                                \
    short8 af[4];                                                                  \
    _Pragma("unroll") for (int mi = 0; mi < 4; ++mi)                               \
      af[mi] = *(const short8a*)&lsm[(P_) * 24576 + (KK_) * 4096 + aoff[mi]];      \
    short8 bf[4];                                                                  \
    _Pragma("unroll") for (int ni = 0; ni < 4; ++ni)                               \
      bf[ni] = *(const short8a*)&lsm[(P_) * 24576 + 8192 + (KK_) * 8192 +          \
                                     boff[ni]];                                    \
    STAGE0; STAGE1;                                                                \
    FENCE();                                                                       \
    __builtin_amdgcn_s_barrier();                                                  \
    FENCE();                                                                       \
    __builtin_amdgcn_s_setprio(1);                                                 \
    _Pragma("unroll") for (int mi = 0; mi < 4; ++mi)                               \
      _Pragma("unroll") for (int ni = 0; ni < 4; ++ni)                             \
        acc[mi][ni] = __builtin_amdgcn_mfma_f32_16x16x32_bf16(                     \
            af[mi], bf[ni], acc[mi][ni], 0, 0, 0);                                 \
    __builtin_amdgcn_s_setprio(0);                                                 \
    FENCE();                                                                       \
    ENDW;                                                                          \
    __builtin_amdgcn_s_barrier();                                                  \
    FENCE();                                                                       \
  }

__global__ __launch_bounds__(512, 2)
void gemm_out(const short* __restrict__ A, const short* __restrict__ B,
              float* __restrict__ Cf, int M, int N, int K) {
  __shared__ alignas(16) short lsm[49152];   // 96 KiB (2 x 24576 shorts)
  const int tid = threadIdx.x;
  const int wave = tid >> 6, lane = tid & 63;
  const int quad = lane >> 4, l16 = lane & 15;
  const int m0 = blockIdx.x * 128, n0 = blockIdx.y * 256;
  const int wm = (wave >> 2) * 64, wn = (wave & 3) * 64;
  const int nK = K >> 6;               // even, >= 2

  int aoff[4], boff[4];
#pragma unroll
  for (int j = 0; j < 4; ++j) {
    int r = wm + j * 16 + l16;
    aoff[j] = r * 32 + (quad ^ ((r >> 1) & 3)) * 8;
  }
#pragma unroll
  for (int ni = 0; ni < 4; ++ni) {
    int r = wn + ni * 16 + l16;
    boff[ni] = r * 32 + (quad ^ ((r >> 1) & 3)) * 8;
  }
  const int r0 = tid >> 2;
  const int qq = (tid & 3) ^ ((r0 >> 1) & 3);   // invariant under row+128
  const short* Asrc = A + (size_t)(m0 + r0) * K + qq * 8;
  const short* Bsrc = B + (size_t)(n0 + r0) * K + qq * 8;

  float4_ acc[4][4];
#pragma unroll
  for (int i = 0; i < 4; i++)
#pragma unroll
    for (int j = 0; j < 4; j++) acc[i][j] = (float4_){0.f, 0.f, 0.f, 0.f};

  // prologue: stage groups 0,1,2; retire group 0 (keep 1,2 in flight)
  STG2(0, 0, 0, 0); STG2(0, 0, 0, 1);
  STG2(0, 1, 0, 0); STG2(0, 1, 0, 1);
  STG2(1, 0, 1, 0); STG2(1, 0, 1, 1);
  FENCE();
  waitv<6>();
  __builtin_amdgcn_s_barrier();
  FENCE();

  for (int t = 0; t < nK; t += 2) {
    PHASED2(0, 0, STG2(1, 1, t + 1, 0), STG2(1, 1, t + 1, 1), WAITG2(2 * t));
    PHASED2(0, 1, STG2(0, 0, t + 2, 0), STG2(0, 0, t + 2, 1), WAITG2(2 * t + 1));
    PHASED2(1, 0, STG2(0, 1, t + 2, 0), STG2(0, 1, t + 2, 1), WAITG2(2 * t + 2));
    PHASED2(1, 1, STG2(1, 0, t + 3, 0), STG2(1, 0, t + 3, 1), WAITG2(2 * t + 3));
  }

#pragma unroll
  for (int mt = 0; mt < 4; ++mt)
#pragma unroll
    for (int ni = 0; ni < 4; ++ni) {
      int row = m0 + wm + mt * 16 + quad * 4;
      int col = n0 + wn + ni * 16 + l16;
      float4_ v = acc[mt][ni];
#pragma unroll
      for (int r = 0; r < 4; r++) Cf[(size_t)(row + r) * N + col] = v[r];
    }
}

// ---------- 3. GQA causal flash attention (no-max softmax; 128-row Q tiles) ----------
// grid (64 = b*16+h, 8 qtiles reversed), 256 threads = 4 waves x (2 groups x 16 q-rows).
// ROUND-6 CHANGE (T14 async-STAGE split, m214v27 +17% on attn): next K/V tile is
// loaded global->REGISTERS during the current tile's compute (QK^T/softmax/PV hides
// the ~200-900cy HBM/L2 latency), then ds_written after the read-barrier. Replaces
// the serial {barrier; global_load_lds x8; barrier(vmcnt0 drain)} per tile, which
// exposed the full load latency every tile. Same barrier count, +32 VGPR (kreg/vreg).
// LDS layout identical: writes land at base+lane*16B, exactly what global_load_lds did.
__global__ __launch_bounds__(256, 2)
void flash(const short* __restrict__ qkv, const short* __restrict__ vt,
           const float* __restrict__ head_scale, short* __restrict__ attn) {
  __shared__ alignas(16) short lK[64 * 128];   // [krow][d-chunk swizzled]
  __shared__ alignas(16) short lV[128 * 64];   // [d][krow-chunk swizzled]
  __shared__ alignas(16) short lP[4][32 * 72]; // per-wave P (32 rows), padded stride 72
  const int tid = threadIdx.x, wave = tid >> 6, lane = tid & 63;
  const int quad = lane >> 4, l16 = lane & 15;
  const int bh = blockIdx.x, b = bh >> 4, h = bh & 15, kv = h >> 2;
  const int qt = 7 - blockIdx.y;               // heavy blocks first
  const int base_w = qt * 128 + wave * 32;     // wave's first q-row
  short8 qf[2][4];
#pragma unroll
  for (int g = 0; g < 2; g++) {
    int qrow = base_w + g * 16 + l16;
    const short* qp = qkv + (size_t)(b * 1024 + qrow) * 3072 + h * 128;
#pragma unroll
    for (int kc = 0; kc < 4; kc++) qf[g][kc] = *(const short8a*)(qp + kc * 32 + quad * 8);
  }
  float4_ O[2][8];
#pragma unroll
  for (int g = 0; g < 2; g++)
#pragma unroll
    for (int i = 0; i < 8; i++) O[g][i] = (float4_){0.f, 0.f, 0.f, 0.f};
  float rsacc[2][4] = {{0.f, 0.f, 0.f, 0.f}, {0.f, 0.f, 0.f, 0.f}};
  const size_t kbase = (size_t)(b * 1024) * 3072 + 2048 + kv * 128;
  const size_t vbase = (size_t)((b * 4 + kv) * 128) * 1024;
  const int slot16 = lane & 15, rr4 = lane >> 4;
  const int slot8 = lane & 7, dr8 = lane >> 3;
  const int nkt = 2 * qt + 2;

  short8 kreg[4], vreg[4];                      // in-flight next tile (T14)
#define LOADT(KT_)                                                              \
  { _Pragma("unroll") for (int cc = 0; cc < 4; ++cc) {                          \
      int r = wave * 16 + cc * 4 + rr4;                                         \
      int c = slot16 ^ (r & 15);                                                \
      kreg[cc] = *(const short8a*)(qkv + kbase +                                \
                    (size_t)((KT_) * 64 + r) * 3072 + c * 8);                   \
    }                                                                           \
    _Pragma("unroll") for (int cc = 0; cc < 4; ++cc) {                          \
      int d = wave * 32 + cc * 8 + dr8;                                         \
      int c = slot8 ^ (d & 7);                                                  \
      vreg[cc] = *(const short8a*)(vt + vbase + (size_t)d * 1024 +              \
                    (KT_) * 64 + c * 8);                                        \
    } }
#define WRITET()                                                                \
  { _Pragma("unroll") for (int cc = 0; cc < 4; ++cc)                            \
      *(short8a*)&lK[(wave * 16 + cc * 4) * 128 + lane * 8] = kreg[cc];         \
    _Pragma("unroll") for (int cc = 0; cc < 4; ++cc)                            \
      *(short8a*)&lV[(wave * 32 + cc * 8) * 64 + lane * 8] = vreg[cc]; }

  LOADT(0);
  WRITET();                                     // compiler inserts vmcnt waits
  __syncthreads();
  for (int kt = 0; kt < nkt; ++kt) {
    if (kt + 1 < nkt) LOADT(kt + 1);            // issue early: hides under compute
    if (kt * 64 <= base_w + 31) {               // wave not fully below diagonal (uniform)
      // S = Q K^T, both groups share kf
      float4_ S[2][4];
#pragma unroll
      for (int st = 0; st < 4; ++st) {
        float4_ s0 = (float4_){0.f, 0.f, 0.f, 0.f}, s1 = s0;
        int kr = st * 16 + l16;
#pragma unroll
        for (int kc = 0; kc < 4; ++kc) {
          int c = kc * 4 + quad;
          short8 kf = *(const short8a*)&lK[kr * 128 + (c ^ (kr & 15)) * 8];
          s0 = __builtin_amdgcn_mfma_f32_16x16x32_bf16(qf[0][kc], kf, s0, 0, 0, 0);
          s1 = __builtin_amdgcn_mfma_f32_16x16x32_bf16(qf[1][kc], kf, s1, 0, 0, 0);
        }
        S[0][st] = s0; S[1][st] = s1;
      }
      // causal mask + exp + P store
#pragma unroll
      for (int g = 0; g < 2; g++) {
        int gbase = base_w + g * 16;
        if (kt * 64 + 63 > gbase) {
#pragma unroll
          for (int st = 0; st < 4; ++st)
#pragma unroll
            for (int r = 0; r < 4; r++)
              if (kt * 64 + st * 16 + l16 > gbase + quad * 4 + r) S[g][st][r] = -1e30f;
        }
#pragma unroll
        for (int st = 0; st < 4; ++st)
#pragma unroll
          for (int r = 0; r < 4; r++) {
            float pv = __expf(S[g][st][r]);
            rsacc[g][r] += pv;
            lP[wave][(g * 16 + quad * 4 + r) * 72 + st * 16 + l16] = f2b(pv);
          }
      }
      short8 pf[2][2];
#pragma unroll
      for (int g = 0; g < 2; g++)
#pragma unroll
        for (int kc2 = 0; kc2 < 2; kc2++)
          pf[g][kc2] = *(const short8a*)&lP[wave][(g * 16 + l16) * 72 + kc2 * 32 + quad * 8];
#pragma unroll
      for (int dt = 0; dt < 8; ++dt) {
        int d = dt * 16 + l16;
#pragma unroll
        for (int kc2 = 0; kc2 < 2; kc2++) {
          int c = kc2 * 4 + quad;
          short8 vf = *(const short8a*)&lV[d * 64 + (c ^ (d & 7)) * 8];
          O[0][dt] = __builtin_amdgcn_mfma_f32_16x16x32_bf16(pf[0][kc2], vf, O[0][dt], 0, 0, 0);
          O[1][dt] = __builtin_amdgcn_mfma_f32_16x16x32_bf16(pf[1][kc2], vf, O[1][dt], 0, 0, 0);
        }
      }
    }
    if (kt + 1 < nkt) {
      __syncthreads();                          // all compute reads of lK/lV done
      WRITET();                                 // vmcnt wait ~0: loads issued a phase ago
      __syncthreads();                          // writes visible
    }
  }
  float hs = head_scale[h];
#pragma unroll
  for (int g = 0; g < 2; g++) {
    float l_i[4];
#pragma unroll
    for (int r = 0; r < 4; r++) {
      float rs = rsacc[g][r];
#pragma unroll
      for (int off = 8; off; off >>= 1) rs += __shfl_xor(rs, off, 64);
      l_i[r] = rs;
    }
    int qrow = base_w + g * 16 + quad * 4;
#pragma unroll
    for (int dt = 0; dt < 8; ++dt) {
      int col = h * 128 + dt * 16 + l16;
#pragma unroll
      for (int r = 0; r < 4; r++) {
        float o = O[g][dt][r] * (hs / l_i[r]);
        attn[(size_t)(b * 1024 + qrow + r) * 2048 + col] = f2b(o);
      }
    }
  }
#undef LOADT
#undef WRITET
}

// ---------- launch ----------
extern "C" void kernel_launch(void* const* d_in, const int* in_sizes, int n_in,
                              void* d_out, int out_size, void* d_ws, size_t ws_size,
                              hipStream_t stream) {
  const float* x  = (const float*)d_in[0];
  const float* Wq = (const float*)d_in[1];
  const float* Wk = (const float*)d_in[2];
  const float* Wv = (const float*)d_in[3];
  const float* Wo = (const float*)d_in[4];
  const float* hs = (const float*)d_in[5];
  float* out = (float*)d_out;
  char* ws = (char*)d_ws;
  // ws layout (64 MB total)
  short* xb    = (short*)(ws);                  // 16 MB  [4096][2048]   (reused as attn)
  short* wqkvt = (short*)(ws + 16777216);       // 12 MB  [3072][2048]
  short* wot   = (short*)(ws + 29360128);       //  8 MB  [2048][2048]
  short* qkv   = (short*)(ws + 37748736);       // 24 MB  [4096][3072] (V cols unused)
  short* vt    = (short*)(ws + 62914560);       //  4 MB  [2048][1024]
  short* attn  = xb;                            // alias: xb dead after GEMM1
  // rope table lives in d_out's tail: d_out (32 MB fp32) is dead until GEMM2 fully overwrites it
  float* rtab  = out + 8257536;                 // 512 KB = 131072 floats

  prep<<<11008, 256, 0, stream>>>(x, Wq, Wk, Wv, Wo, xb, wqkvt, wot, rtab);
  gemm_rope<<<dim3(32, 24), 256, 0, stream>>>(xb, wqkvt, qkv, rtab, vt, 4096, 3072, 2048);
  flash<<<dim3(64, 8), 256, 0, stream>>>(qkv, vt, hs, attn);
  gemm_out<<<dim3(32, 8), 512, 0, stream>>>(attn, wot, out, 4096, 2048, 2048);
}